// Round 21
// baseline (35.727 us; speedup 1.0000x reference)
//
#include <hip/hip_runtime.h>
#include <math.h>

namespace {

constexpr int Bn = 2, Hn = 128, Wn = 128, Cn = 256, Vn = 64;

__device__ __forceinline__ void load8(float* r, const float* p) {
    float4 a = *(const float4*)(p);
    float4 b = *(const float4*)(p + 4);
    r[0]=a.x; r[1]=a.y; r[2]=a.z; r[3]=a.w;
    r[4]=b.x; r[5]=b.y; r[6]=b.z; r[7]=b.w;
}

// DPP-based add of a row-permuted copy (VALU pipe, not DS). CTRL is a
// compile-time template arg. 0xB1=xor1, 0x4E=xor2, 0x124=row_ror:4,
// 0x128=row_ror:8.
template <int CTRL>
__device__ __forceinline__ float row_add(float v) {
    int sh = __builtin_amdgcn_update_dpp(0, __float_as_int(v), CTRL, 0xF, 0xF, true);
    return v + __int_as_float(sh);
}

// Sum over the 32 split lanes (lane bits 0..4), result in all lanes.
// 4 DPP adds (VALU) + ONE ds_swizzle xor16 (DS) — R12-proven.
__device__ __forceinline__ float split_reduce(float v) {
    v = row_add<0xB1>(v);
    v = row_add<0x4E>(v);
    v = row_add<0x124>(v);
    v = row_add<0x128>(v);
    v += __int_as_float(__builtin_amdgcn_ds_swizzle(__float_as_int(v), 0x401F)); // xor16
    return v;
}

// R20 base (35.4us: 8 pairs x 32 splits, DPP reduce, online softmax, hoisted
// value loads) with ONE change: PER-WAVE di PHASE STAGGER. Evidence: VALU
// 42% + L1 ~45% with sum ~= dur means the two pipes barely overlap even
// though residency appears ample (VGPR 60 <= 64-bin). Hypothesis: identical
// barrier-free waves self-align into a convoy - all issue the score-load
// burst together (L1 saturated, VALU idle), then all compute (VALU busy,
// L1 idle). Starting wave w's di loop at phase w (mod 5) decorrelates the
// phases so one wave's load burst overlaps another's reduce/softmax VALU.
// Online softmax is order-independent (max/sum commute up to fp rounding,
// ~1e-6 << 0.101 threshold).
__global__ __launch_bounds__(256)
void local_attn_kernel(const float* __restrict__ mainp,
                       const float* __restrict__ mainv,
                       const float* __restrict__ refp,
                       const float* __restrict__ refv,
                       float* __restrict__ outp)
{
    const int t = threadIdx.x;
    const int s = t & 31;       // channel split 0..31 (8 ch each)
    const int g = t >> 5;       // pixel-pair 0..7
    const int blk = blockIdx.x; // 0 .. 2047
    const int seg = blk & 7;
    const int h   = (blk >> 3) & (Hn - 1);
    const int b   = blk >> 10;
    const int w0  = seg * 16 + g * 2;   // px0 = w0, px1 = w0+1
    const int rowbase = b * Hn + h;
    const int phase = (t >> 6) + (blk & 1);   // wave id (+block parity): 0..4

    // main channels: 8 each for px0/px1 (ch = s*8 .. s*8+7)
    float m0[8], m1[8];
    const float* mp = mainp + ((size_t)rowbase * Wn + w0) * Cn + s * 8;
    load8(m0, mp);
    load8(m1, mp + Cn);

    // self scores (slot 25)
    float self0 = 0.f, self1 = 0.f;
    #pragma unroll
    for (int c = 0; c < 8; ++c) {
        self0 = fmaf(m0[c], m0[c], self0);
        self1 = fmaf(m1[c], m1[c], self1);
    }
    self0 = split_reduce(self0);
    self1 = split_reduce(self1);

    // online-softmax state seeded with the self slot (weight exp(0)=1)
    float mx0 = self0, mx1 = self1, den0 = 1.f, den1 = 1.f;
    float acc0[2], acc1[2];
    {
        const float* mvp = mainv + ((size_t)rowbase * Wn + w0) * Vn + s * 2;
        float2 a = *(const float2*)(mvp);
        float2 c = *(const float2*)(mvp + Vn);
        acc0[0] = a.x; acc0[1] = a.y;
        acc1[0] = c.x; acc1[1] = c.y;
    }

    #pragma unroll 1
    for (int dd = 0; dd < 5; ++dd) {
        int di = dd + phase;
        if (di >= 5) di -= 5;               // wave-uniform (SGPR) rotation
        const int hh = h + di - 2;
        const bool rowok = (unsigned)hh < (unsigned)Hn;
        const size_t rbase = (size_t)(b * Hn + (rowok ? hh : 0)) * Wn;
        const float* rp = refp + rbase * Cn + s * 8;

        // ---- scores: 6 shared column loads serve both pixels ----
        float sc0[5], sc1[5];
        #pragma unroll
        for (int o = 0; o < 6; ++o) {
            const int col = w0 - 2 + o;
            const bool ok = rowok && (unsigned)col < (unsigned)Wn;
            float r[8];
            #pragma unroll
            for (int c = 0; c < 8; ++c) r[c] = 0.f;
            if (ok) load8(r, rp + (size_t)col * Cn);
            if (o < 5) {
                float a = 0.f;
                #pragma unroll
                for (int c = 0; c < 8; ++c) a = fmaf(m0[c], r[c], a);
                sc0[o] = a;
            }
            if (o >= 1) {
                float a = 0.f;
                #pragma unroll
                for (int c = 0; c < 8; ++c) a = fmaf(m1[c], r[c], a);
                sc1[o - 1] = a;
            }
        }

        // ---- hoisted value loads: latency overlaps reduce + softmax ----
        const float* rvp = refv + rbase * Vn + s * 2;
        float2 rv[6];
        #pragma unroll
        for (int o = 0; o < 6; ++o) {
            const int col = w0 - 2 + o;
            rv[o] = make_float2(0.f, 0.f);
            if (rowok && (unsigned)col < (unsigned)Wn)
                rv[o] = *(const float2*)(rvp + (size_t)col * Vn);
        }

        // reduce partial dots across the 32 split lanes
        #pragma unroll
        for (int k = 0; k < 5; ++k) {
            sc0[k] = split_reduce(sc0[k]);
            sc1[k] = split_reduce(sc1[k]);
        }

        // ---- online softmax row update (both pixels)
        const float rm0 = fmaxf(fmaxf(fmaxf(sc0[0], sc0[1]), fmaxf(sc0[2], sc0[3])), sc0[4]);
        const float rm1 = fmaxf(fmaxf(fmaxf(sc1[0], sc1[1]), fmaxf(sc1[2], sc1[3])), sc1[4]);
        const float nm0 = fmaxf(mx0, rm0), nm1 = fmaxf(mx1, rm1);
        const float e0 = __expf(mx0 - nm0), e1 = __expf(mx1 - nm1);
        float sum0 = 0.f, sum1 = 0.f;
        #pragma unroll
        for (int k = 0; k < 5; ++k) {
            sc0[k] = __expf(sc0[k] - nm0); sum0 += sc0[k];
            sc1[k] = __expf(sc1[k] - nm1); sum1 += sc1[k];
        }
        den0 = den0 * e0 + sum0;
        den1 = den1 * e1 + sum1;
        acc0[0] *= e0; acc0[1] *= e0;
        acc1[0] *= e1; acc1[1] *= e1;
        mx0 = nm0; mx1 = nm1;

        // ---- values: FMAs from prefetched rv ----
        #pragma unroll
        for (int o = 0; o < 6; ++o) {
            if (o < 5) {
                const float wkj = sc0[o];
                acc0[0] = fmaf(wkj, rv[o].x, acc0[0]);
                acc0[1] = fmaf(wkj, rv[o].y, acc0[1]);
            }
            if (o >= 1) {
                const float wkj = sc1[o - 1];
                acc1[0] = fmaf(wkj, rv[o].x, acc1[0]);
                acc1[1] = fmaf(wkj, rv[o].y, acc1[1]);
            }
        }
    }

    const float inv0 = 1.f / den0, inv1 = 1.f / den1;
    float* op = outp + ((size_t)rowbase * Wn + w0) * Vn + s * 2;
    float2 o0, o1;
    o0.x = acc0[0] * inv0; o0.y = acc0[1] * inv0;
    o1.x = acc1[0] * inv1; o1.y = acc1[1] * inv1;
    *(float2*)(op)      = o0;
    *(float2*)(op + Vn) = o1;
}

} // namespace

extern "C" void kernel_launch(void* const* d_in, const int* in_sizes, int n_in,
                              void* d_out, int out_size, void* d_ws, size_t ws_size,
                              hipStream_t stream)
{
    const float* mainp = (const float*)d_in[0];
    const float* mainv = (const float*)d_in[1];
    const float* refp  = (const float*)d_in[2];
    const float* refv  = (const float*)d_in[3];
    float* outp = (float*)d_out;

    dim3 grid(Bn * Hn * 8);   // 2048 blocks: one per 16-pixel row segment
    dim3 block(256);          // 8 pairs x 32 splits
    hipLaunchKernelGGL(local_attn_kernel, grid, block, 0, stream,
                       mainp, mainv, refp, refv, outp);
}